// Round 1
// baseline (234.787 us; speedup 1.0000x reference)
//
#include <hip/hip_runtime.h>
#include <math.h>

// CPHASE on qubits (0,1) of a 22-qubit state, batch B=4 (innermost axis).
// Flat float index: (((q01 * 2^20 + rest) * 4) + b); one v4f = one amplitude's
// 4 batch lanes. v4f index space is [0, 2^22); the q01==3 quarter is
// [3*2^20, 2^22) and gets the per-batch phase exp(i*theta[b]); rest is a copy.
//
// MLP-tuned version: 2^20 threads, each owning 4 v4f chunks at stride 2^20.
// Because t < 2^20, chunk i==3 is EXACTLY the phase quarter -> the runtime
// branch from the previous version is gone (fully uniform, compile-time).
// All 8 reads (re+im for 4 chunks) are issued before any dependent store:
// 8 outstanding 16B loads/thread vs 2 before -- 4x the in-flight read volume,
// which is what the previous version lacked vs the 6.8 TB/s fill kernels
// sharing the same capture (ours ran at ~4.1 TB/s effective).
//
// Phase factors via native __sincosf (v_sin_f32/v_cos_f32, input-scaled):
// theta address is wave-uniform -> scalar loads; trans-op latency hides
// under the vector loads. VALU is ~5% busy, so this is free.

typedef float v4f __attribute__((ext_vector_type(4)));

#define N_ELEMS (1u << 24)          // 2^22 amplitudes * 4 batch floats
#define N_VEC   (N_ELEMS / 4u)      // 2^22 v4f per array
#define STRIDE  (1u << 20)          // total threads; chunk i at t + i*STRIDE

__global__ __launch_bounds__(256)
void CPHASE_34583076667990_kernel(const v4f* __restrict__ re_in,
                                  const v4f* __restrict__ im_in,
                                  const float* __restrict__ theta,
                                  v4f* __restrict__ out_re,
                                  v4f* __restrict__ out_im) {
    const unsigned t = blockIdx.x * blockDim.x + threadIdx.x;   // [0, 2^20)

    // Phase factors first: wave-uniform scalar loads + 8 trans ops, all of
    // which overlap the vector-load latency below.
    v4f c, s;
    {
        float sv, cv;
        __sincosf(theta[0], &sv, &cv); c.x = cv; s.x = sv;
        __sincosf(theta[1], &sv, &cv); c.y = cv; s.y = sv;
        __sincosf(theta[2], &sv, &cv); c.z = cv; s.z = sv;
        __sincosf(theta[3], &sv, &cv); c.w = cv; s.w = sv;
    }

    // Issue all 8 independent reads up front (8 outstanding 16B loads/thread).
    v4f r0 = __builtin_nontemporal_load(&re_in[t + 0u * STRIDE]);
    v4f i0 = __builtin_nontemporal_load(&im_in[t + 0u * STRIDE]);
    v4f r1 = __builtin_nontemporal_load(&re_in[t + 1u * STRIDE]);
    v4f i1 = __builtin_nontemporal_load(&im_in[t + 1u * STRIDE]);
    v4f r2 = __builtin_nontemporal_load(&re_in[t + 2u * STRIDE]);
    v4f i2 = __builtin_nontemporal_load(&im_in[t + 2u * STRIDE]);
    v4f r3 = __builtin_nontemporal_load(&re_in[t + 3u * STRIDE]);
    v4f i3 = __builtin_nontemporal_load(&im_in[t + 3u * STRIDE]);

    // Copy chunks 0..2 (q01 = 0,1,2): store as soon as each pair lands.
    __builtin_nontemporal_store(r0, &out_re[t + 0u * STRIDE]);
    __builtin_nontemporal_store(i0, &out_im[t + 0u * STRIDE]);
    __builtin_nontemporal_store(r1, &out_re[t + 1u * STRIDE]);
    __builtin_nontemporal_store(i1, &out_im[t + 1u * STRIDE]);
    __builtin_nontemporal_store(r2, &out_re[t + 2u * STRIDE]);
    __builtin_nontemporal_store(i2, &out_im[t + 2u * STRIDE]);

    // Chunk 3 (q01 == 3): complex rotation by exp(i*theta[b]).
    v4f nr = r3 * c - i3 * s;
    v4f ni = r3 * s + i3 * c;
    __builtin_nontemporal_store(nr, &out_re[t + 3u * STRIDE]);
    __builtin_nontemporal_store(ni, &out_im[t + 3u * STRIDE]);
}

extern "C" void kernel_launch(void* const* d_in, const int* in_sizes, int n_in,
                              void* d_out, int out_size, void* d_ws, size_t ws_size,
                              hipStream_t stream) {
    const float* re    = (const float*)d_in[0];
    const float* im    = (const float*)d_in[1];
    const float* theta = (const float*)d_in[2];
    float* out = (float*)d_out;

    dim3 block(256);
    dim3 grid(STRIDE / 256);   // 4096 blocks, one-shot (no tail: 2^20 threads)
    CPHASE_34583076667990_kernel<<<grid, block, 0, stream>>>(
        (const v4f*)re, (const v4f*)im, theta,
        (v4f*)out, (v4f*)(out + N_ELEMS));
}